// Round 14
// baseline (409.411 us; speedup 1.0000x reference)
//
#include <hip/hip_runtime.h>
#include <math.h>

typedef __attribute__((ext_vector_type(8))) short short8;
typedef __attribute__((ext_vector_type(4))) float f32x4;

#define UNITS 512
#define DIN 128

// ws float offsets:
#define WS_COLSA  0        // 8 slots x 128, colsum(A), atomic (zeroed)
#define WS_SCALE  1024     // 512
#define WS_SHIFT  1536     // 512
#define WS_ESLOT  2048     // 512 entropy slots, atomic (zeroed)
#define WS_GF     2560     // 16384, G final (128x128)
#define WS_WHI    19456    // 65536 ushorts (32768 floats)
#define WS_WLO    52224    // 65536 ushorts
#define N_ESLOT   512
#define WS_ZERO_FLOATS 2560

#define GRAM_BLOCKS 512    // G partials: GRAM_BLOCKS x 16384 floats in d_out scratch
#define CAP 32             // per-row candidate capacity (LDS list), stride 33

__device__ __forceinline__ unsigned short f2bf(float f) {
    unsigned u = __float_as_uint(f);
    unsigned r = (u + 0x7FFFu + ((u >> 16) & 1u)) >> 16;   // RNE
    return (unsigned short)r;
}
__device__ __forceinline__ float bf2f(unsigned short h) {
    return __uint_as_float(((unsigned)h) << 16);
}

// K1a: Gram partials G_b = A_b^T A_b (3-term split-bf16 MFMA) + colsum(A).
__global__ __launch_bounds__(256) void k1a_gram(const float* __restrict__ A,
                                                float* __restrict__ Gpart,
                                                float* __restrict__ ws, int Brows)
{
    __shared__ float As[32][133];
    __shared__ float s_lds[128];
    const int t = threadIdx.x;
    const int wave = t >> 6, lane = t & 63, lg = lane >> 4, lm = lane & 15;
    const int rowsPerBlk = Brows / GRAM_BLOCKS;   // 256
    const int r0 = blockIdx.x * rowsPerBlk;

    if (t < 128) s_lds[t] = 0.f;
    float s_part[4] = {0.f, 0.f, 0.f, 0.f};

    f32x4 acc[16];
#pragma unroll
    for (int i = 0; i < 16; ++i) acc[i] = (f32x4){0.f, 0.f, 0.f, 0.f};

    for (int kk = 0; kk < rowsPerBlk; kk += 32) {
        __syncthreads();
#pragma unroll
        for (int i = 0; i < 4; ++i) {
            int fi = t + i * 256;
            int row = fi >> 5, c4 = (fi & 31) * 4;
            float4 v = *(const float4*)(A + (size_t)(r0 + kk + row) * DIN + c4);
            *(float4*)&As[row][c4] = v;
            s_part[0] += v.x; s_part[1] += v.y; s_part[2] += v.z; s_part[3] += v.w;
        }
        __syncthreads();

        short8 fh[8], fl[8];
#pragma unroll
        for (int f = 0; f < 8; ++f) {
#pragma unroll
            for (int j = 0; j < 8; ++j) {
                float v = As[lg * 8 + j][f * 16 + lm];
                unsigned uv = __float_as_uint(v);
                float lo = v - __uint_as_float(uv & 0xFFFF0000u);
                fh[f][j] = (short)(uv >> 16);
                fl[f][j] = (short)(__float_as_uint(lo) >> 16);
            }
        }
        short8 ah0, al0, ah1, al1;
#pragma unroll
        for (int j = 0; j < 8; ++j) {
            float v0 = As[lg * 8 + j][wave * 32 + lm];
            float v1 = As[lg * 8 + j][wave * 32 + 16 + lm];
            unsigned u0 = __float_as_uint(v0), u1 = __float_as_uint(v1);
            float l0 = v0 - __uint_as_float(u0 & 0xFFFF0000u);
            float l1 = v1 - __uint_as_float(u1 & 0xFFFF0000u);
            ah0[j] = (short)(u0 >> 16);
            al0[j] = (short)(__float_as_uint(l0) >> 16);
            ah1[j] = (short)(u1 >> 16);
            al1[j] = (short)(__float_as_uint(l1) >> 16);
        }

#pragma unroll
        for (int tj = 0; tj < 8; ++tj) {
            acc[tj]     = __builtin_amdgcn_mfma_f32_16x16x32_bf16(al0, fh[tj], acc[tj], 0, 0, 0);
            acc[tj]     = __builtin_amdgcn_mfma_f32_16x16x32_bf16(ah0, fl[tj], acc[tj], 0, 0, 0);
            acc[tj]     = __builtin_amdgcn_mfma_f32_16x16x32_bf16(ah0, fh[tj], acc[tj], 0, 0, 0);
            acc[8 + tj] = __builtin_amdgcn_mfma_f32_16x16x32_bf16(al1, fh[tj], acc[8 + tj], 0, 0, 0);
            acc[8 + tj] = __builtin_amdgcn_mfma_f32_16x16x32_bf16(ah1, fl[tj], acc[8 + tj], 0, 0, 0);
            acc[8 + tj] = __builtin_amdgcn_mfma_f32_16x16x32_bf16(ah1, fh[tj], acc[8 + tj], 0, 0, 0);
        }
    }

#pragma unroll
    for (int j = 0; j < 4; ++j) atomicAdd(&s_lds[(t & 31) * 4 + j], s_part[j]);
    __syncthreads();
    if (t < 128) atomicAdd(ws + WS_COLSA + (blockIdx.x & 7) * 128 + t, s_lds[t]);

    float* Gs = Gpart + (size_t)blockIdx.x * 16384;
#pragma unroll
    for (int a2 = 0; a2 < 2; ++a2) {
#pragma unroll
        for (int tj = 0; tj < 8; ++tj) {
#pragma unroll
            for (int g = 0; g < 4; ++g) {
                int gi = (2 * wave + a2) * 16 + lg * 4 + g;
                int gj = tj * 16 + lm;
                Gs[gi * 128 + gj] = acc[a2 * 8 + tj][g];
            }
        }
    }
}

// K1b: reduce GRAM_BLOCKS partials -> G final in ws
__global__ __launch_bounds__(256) void k1b_sumG(const float* __restrict__ Gpart,
                                                float* __restrict__ ws)
{
    int i = blockIdx.x * 256 + threadIdx.x;   // 0..16383
    float v = 0.f;
#pragma unroll 8
    for (int s = 0; s < GRAM_BLOCKS; ++s) v += Gpart[(size_t)s * 16384 + i];
    ws[WS_GF + i] = v;
}

// K2: per-column BN stats from Gram + fused W'-pack (W' = W*scale).
__global__ __launch_bounds__(128) void k2_finalize(
    const float* __restrict__ W, const float* __restrict__ gamma,
    const float* __restrict__ beta, float* __restrict__ ws,
    unsigned short* __restrict__ Whi, unsigned short* __restrict__ Wlo, int Brows)
{
    __shared__ float wcol[128];
    __shared__ float red[4];
    __shared__ float sres;
    const int t = threadIdx.x, n = blockIdx.x;
    wcol[t] = W[(size_t)t * UNITS + n];
    __syncthreads();
    const float* GF = ws + WS_GF;
    float q = 0.f;
#pragma unroll 8
    for (int i = 0; i < 128; ++i) q += GF[i * 128 + t] * wcol[i];
    q *= wcol[t];
    float csa = 0.f;
#pragma unroll
    for (int sl = 0; sl < 8; ++sl) csa += ws[WS_COLSA + sl * 128 + t];
    float mp = csa * wcol[t];
#pragma unroll
    for (int off = 32; off; off >>= 1) {
        q  += __shfl_xor(q, off, 64);
        mp += __shfl_xor(mp, off, 64);
    }
    if ((t & 63) == 0) { red[(t >> 6) * 2] = q; red[(t >> 6) * 2 + 1] = mp; }
    __syncthreads();
    if (t == 0) {
        float sumsq = red[0] + red[2], ssum = red[1] + red[3];
        float invB = 1.0f / (float)Brows;
        float mean = ssum * invB;
        float var  = sumsq * invB - mean * mean;
        float rstd = rsqrtf(var + 1e-3f);
        float sc   = rstd * gamma[n];
        ws[WS_SCALE + n] = sc;
        ws[WS_SHIFT + n] = beta[n] - mean * sc;
        sres = sc;
    }
    __syncthreads();
    float v = wcol[t] * sres;
    int c = t >> 5, j = t & 7, lane = ((t >> 3) & 3) * 16 + (n & 15), t8 = n >> 4;
    int dst = (((c * 32 + t8) * 64 + lane) << 3) + j;
    unsigned short hi = f2bf(v);
    Whi[dst] = hi;
    Wlo[dst] = f2bf(v - bf2f(hi));
}

// K3: swapped-operand fused kernel, pair-split, 3-waves/SIMD occupancy target.
// Block = 256 thr = 4 waves = 2 pairs x 16 rows = 32 rows. Wave (pair,H):
// rows pair*16..+15 x cols H*256..+255 (acc = 16 tiles = 64 regs).
// 16 stages of 16 KB: s = (c = s>>2, Hs = (s>>1)&1, which = s&1); dbuf 32 KB.
// Tail: row-keyed LDS compaction, solver waves own 8 rows (8 lanes/row).
__global__ __launch_bounds__(256, 3) void k3_fused(
    const float* __restrict__ A, const unsigned short* __restrict__ Whi,
    const unsigned short* __restrict__ Wlo, const float* __restrict__ prior,
    float* __restrict__ out, float* __restrict__ ws)
{
    __shared__ short8 wb[2][16][64];     // 32 KB staging; aliased as cand[] after GEMM
    __shared__ float mrow[4][16];
    __shared__ float taurow[32];
    __shared__ float SKl[4][16][2];
    __shared__ int   cnt[32];
    __shared__ int   ovfflag;
    float* cand = (float*)wb;            // cand[r*33 + slot], 32x33 floats = 4.2 KB

    const int tid = threadIdx.x;
    const int wave = tid >> 6, lane = tid & 63, lg = lane >> 4, lm = lane & 15;
    const int pair = wave >> 1;          // 0..1: rows pair*16..+15
    const int H = wave & 1;              // col half: cols H*256..+255
    const int rl = pair * 16 + lm;       // block-local row of this lane
    const size_t grow = (size_t)blockIdx.x * 32 + rl;

    // A fragments (B-operand of swapped mfma): row = grow, k = lg*8+j
    short8 ahi[4], alo[4];
    const float* arow = A + grow * DIN + lg * 8;
#pragma unroll
    for (int c = 0; c < 4; ++c) {
        float4 f0 = *(const float4*)(arow + c * 32);
        float4 f1 = *(const float4*)(arow + c * 32 + 4);
        float fv[8] = {f0.x, f0.y, f0.z, f0.w, f1.x, f1.y, f1.z, f1.w};
#pragma unroll
        for (int j = 0; j < 8; ++j) {
            unsigned uv = __float_as_uint(fv[j]);
            float lo = fv[j] - __uint_as_float(uv & 0xFFFF0000u);
            ahi[c][j] = (short)(uv >> 16);
            alo[c][j] = (short)(__float_as_uint(lo) >> 16);
        }
    }

    // stage s: 16 KB = 1024 x 16B chunks over 256 thr (4/thread).
    // q = i*256+tid: tile = q>>6 = i*4+wave (uniform/wave), slot = lane.
#define K3_STAGE(s, buf)                                                          \
    {                                                                             \
        const unsigned short* src_ = (((s) & 1) ? Wlo : Whi)                      \
            + (size_t)(((((s) >> 2) * 32) + ((((s) >> 1) & 1) * 16)) * 512);      \
        _Pragma("unroll")                                                         \
        for (int i_ = 0; i_ < 4; ++i_) {                                          \
            int q_ = i_ * 256 + tid;                                              \
            __builtin_amdgcn_global_load_lds(                                     \
                (const __attribute__((address_space(1))) void*)(src_ + (size_t)q_ * 8), \
                (__attribute__((address_space(3))) void*)&wb[buf][q_ >> 6][q_ & 63], \
                16, 0, 0);                                                        \
        }                                                                         \
    }

    // acc[t][g] = X_bn[r][n = H*256 + t*16 + lg*4 + g]; init = shift[n]
    f32x4 acc[16];
#pragma unroll
    for (int t = 0; t < 16; ++t)
        acc[t] = *(const f32x4*)(ws + WS_SHIFT + H * 256 + t * 16 + lg * 4);

    K3_STAGE(0, 0);
    asm volatile("s_waitcnt vmcnt(0)" ::: "memory");
    __syncthreads();

#pragma unroll
    for (int s = 0; s < 16; ++s) {
        // issue next stage into the other buffer
        if (s == 0) { K3_STAGE(1, 1); }
        else if (s == 1) { K3_STAGE(2, 0); }
        else if (s == 2) { K3_STAGE(3, 1); }
        else if (s == 3) { K3_STAGE(4, 0); }
        else if (s == 4) { K3_STAGE(5, 1); }
        else if (s == 5) { K3_STAGE(6, 0); }
        else if (s == 6) { K3_STAGE(7, 1); }
        else if (s == 7) { K3_STAGE(8, 0); }
        else if (s == 8) { K3_STAGE(9, 1); }
        else if (s == 9) { K3_STAGE(10, 0); }
        else if (s == 10) { K3_STAGE(11, 1); }
        else if (s == 11) { K3_STAGE(12, 0); }
        else if (s == 12) { K3_STAGE(13, 1); }
        else if (s == 13) { K3_STAGE(14, 0); }
        else if (s == 14) { K3_STAGE(15, 1); }
        const int buf = s & 1, c = s >> 2, Hs = (s >> 1) & 1, which = s & 1;
        if (Hs == H) {   // wave-uniform branch; s terms compile-time
            if (which == 0) {
#pragma unroll
                for (int t = 0; t < 16; ++t) {
                    short8 h = wb[buf][t][lane];
                    acc[t] = __builtin_amdgcn_mfma_f32_16x16x32_bf16(h, alo[c], acc[t], 0, 0, 0);
                    acc[t] = __builtin_amdgcn_mfma_f32_16x16x32_bf16(h, ahi[c], acc[t], 0, 0, 0);
                }
            } else {
#pragma unroll
                for (int t = 0; t < 16; ++t) {
                    short8 l = wb[buf][t][lane];
                    acc[t] = __builtin_amdgcn_mfma_f32_16x16x32_bf16(l, ahi[c], acc[t], 0, 0, 0);
                }
            }
        }
        if (s < 15) {
            asm volatile("s_waitcnt vmcnt(0)" ::: "memory");
            __syncthreads();
        }
    }

    // prior-mul + wave-local row max over this wave's 256 cols
    const float* prow = prior + grow * UNITS + H * 256 + lg * 4;
    float m = -3.4e38f;
#pragma unroll
    for (int t = 0; t < 16; ++t) {
        float4 p = *(const float4*)(prow + t * 16);
        acc[t][0] *= p.x; acc[t][1] *= p.y; acc[t][2] *= p.z; acc[t][3] *= p.w;
        m = fmaxf(m, fmaxf(fmaxf(acc[t][0], acc[t][1]), fmaxf(acc[t][2], acc[t][3])));
    }
    m = fmaxf(m, __shfl_xor(m, 16, 64));
    m = fmaxf(m, __shfl_xor(m, 32, 64));
    if (lane < 16) mrow[wave][lm] = m;
    if (tid < 32) cnt[tid] = 0;
    if (tid == 0) ovfflag = 0;
    __syncthreads();   // B1: retires wb for cand aliasing; publishes mrow/cnt/flag

    // pair max -> tau0 per row
    const float tau0 = fmaxf(mrow[pair * 2][lm], mrow[pair * 2 + 1][lm]) - 1.0f;
    if (lane < 16 && H == 0) taurow[rl] = tau0;

    // candidate compaction into row-keyed lists (few atomics per row)
#pragma unroll
    for (int t = 0; t < 16; ++t) {
#pragma unroll
        for (int g = 0; g < 4; ++g) {
            float v = acc[t][g];
            if (v > tau0) {
                int idx = atomicAdd(&cnt[rl], 1);
                if (idx < CAP) cand[rl * 33 + idx] = v;
            }
        }
    }
    __syncthreads();   // B2: lists + counts + taurow visible

    // solver mapping: wave solves rows wave*8..+7; 8 lanes per row
    const int sr = wave * 8 + (lane >> 3);
    const int ss = lane & 7;
    const int ncand = cnt[sr];
    if (ncand > CAP) ovfflag = 1;    // benign race
    __syncthreads();   // B3: flag uniform
    const bool ovf = (ovfflag != 0);

    float ent = 0.f;
    float tauF;
    if (!ovf) {
        float tau = taurow[sr];
        for (int it = 0; it < 16; ++it) {
            float S = 0.f, K = 0.f;
#pragma unroll
            for (int i = 0; i < 4; ++i) {
                int idx = ss + 8 * i;
                if (idx < ncand) {
                    float v = cand[sr * 33 + idx];
                    if (v > tau) { S += v; K += 1.f; }
                }
            }
            S += __shfl_xor(S, 1, 64); S += __shfl_xor(S, 2, 64); S += __shfl_xor(S, 4, 64);
            K += __shfl_xor(K, 1, 64); K += __shfl_xor(K, 2, 64); K += __shfl_xor(K, 4, 64);
            float nt = (S - 1.0f) / K;
            int chg = (nt > tau);
            if (chg) tau = nt;
            if (__ballot(chg) == 0ull) break;
        }
        // entropy over support only (zero-mask terms contribute exactly 0)
#pragma unroll
        for (int i = 0; i < 4; ++i) {
            int idx = ss + 8 * i;
            if (idx < ncand) {
                float v = cand[sr * 33 + idx] - tau;
                if (v > 0.f) ent -= v * __logf(v + 1e-15f);
            }
        }
#pragma unroll
        for (int off = 1; off <= 32; off <<= 1) ent += __shfl_xor(ent, off, 64);
        if (ss == 0) taurow[sr] = tau;
        __syncthreads();   // B4: final taus visible
        tauF = taurow[rl];
    } else {
        // fallback: pair-wise full-scan Newton, fixed 24 iters (uniform barriers)
        float tau = tau0;
        for (int it = 0; it < 24; ++it) {
            float S = 0.f, K = 0.f;
#pragma unroll
            for (int t = 0; t < 16; ++t) {
#pragma unroll
                for (int g = 0; g < 4; ++g) {
                    float v = acc[t][g];
                    if (v > tau) { S += v; K += 1.f; }
                }
            }
            S += __shfl_xor(S, 16, 64); S += __shfl_xor(S, 32, 64);
            K += __shfl_xor(K, 16, 64); K += __shfl_xor(K, 32, 64);
            if (lane < 16) { SKl[wave][lm][0] = S; SKl[wave][lm][1] = K; }
            __syncthreads();
            float St = SKl[pair * 2][lm][0] + SKl[pair * 2 + 1][lm][0];
            float Kt = SKl[pair * 2][lm][1] + SKl[pair * 2 + 1][lm][1];
            float nt = (St - 1.0f) / Kt;
            if (nt > tau) tau = nt;
            __syncthreads();
        }
        tauF = tau;
#pragma unroll
        for (int t = 0; t < 16; ++t) {
#pragma unroll
            for (int g = 0; g < 4; ++g) {
                float v = fmaxf(acc[t][g] - tauF, 0.f);
                if (v > 0.f) ent -= v * __logf(v + 1e-15f);
            }
        }
#pragma unroll
        for (int off = 1; off <= 32; off <<= 1) ent += __shfl_xor(ent, off, 64);
    }

    // mask write
    float* orow = out + grow * UNITS + H * 256 + lg * 4;
#pragma unroll
    for (int t = 0; t < 16; ++t) {
        float4 o;
        o.x = fmaxf(acc[t][0] - tauF, 0.f);
        o.y = fmaxf(acc[t][1] - tauF, 0.f);
        o.z = fmaxf(acc[t][2] - tauF, 0.f);
        o.w = fmaxf(acc[t][3] - tauF, 0.f);
        *(float4*)(orow + t * 16) = o;
    }

    if (lane == 0)
        atomicAdd(&ws[WS_ESLOT + ((blockIdx.x * 4 + wave) & (N_ESLOT - 1))], ent);
#undef K3_STAGE
}

// K4: reduce entropy slots -> scalar loss
__global__ void k4_loss(const float* __restrict__ ws, float* __restrict__ out_loss,
                        int Brows)
{
    __shared__ float sh[512];
    int t = threadIdx.x;
    sh[t] = ws[WS_ESLOT + t];
    __syncthreads();
    for (int s = 256; s > 0; s >>= 1) {
        if (t < s) sh[t] += sh[t + s];
        __syncthreads();
    }
    if (t == 0) out_loss[0] = 1e-3f * (sh[0] / (float)Brows) * (1.0f / 3.0f);
}

extern "C" void kernel_launch(void* const* d_in, const int* in_sizes, int n_in,
                              void* d_out, int out_size, void* d_ws, size_t ws_size,
                              hipStream_t stream)
{
    const float* inputs = (const float*)d_in[0];
    const float* prior  = (const float*)d_in[1];
    const float* Wm     = (const float*)d_in[2];
    const float* gamma  = (const float*)d_in[3];
    const float* beta   = (const float*)d_in[4];
    float* out = (float*)d_out;
    float* ws  = (float*)d_ws;
    unsigned short* Whi = (unsigned short*)(ws + WS_WHI);
    unsigned short* Wlo = (unsigned short*)(ws + WS_WLO);
    const int Brows = in_sizes[1] / UNITS;   // 131072

    // d_out doubles as Gram-partial scratch (33.5 MB) before k3 overwrites it.
    float* Gpart = out;

    hipMemsetAsync(ws, 0, WS_ZERO_FLOATS * sizeof(float), stream);

    k1a_gram<<<GRAM_BLOCKS, 256, 0, stream>>>(inputs, Gpart, ws, Brows);
    k1b_sumG<<<64, 256, 0, stream>>>(Gpart, ws);
    k2_finalize<<<UNITS, 128, 0, stream>>>(Wm, gamma, beta, ws, Whi, Wlo, Brows);
    k3_fused<<<Brows / 32, 256, 0, stream>>>(inputs, Whi, Wlo, prior, out, ws);
    k4_loss<<<1, N_ESLOT, 0, stream>>>(ws, out + (size_t)Brows * UNITS, Brows);
}

// Round 15
// 340.979 us; speedup vs baseline: 1.2007x; 1.2007x over previous
//
#include <hip/hip_runtime.h>
#include <math.h>

typedef __attribute__((ext_vector_type(8))) short short8;
typedef __attribute__((ext_vector_type(4))) float f32x4;

#define UNITS 512
#define DIN 128

// ws float offsets:
#define WS_COLSA  0        // 8 slots x 128, colsum(A), atomic (zeroed)
#define WS_SCALE  1024     // 512
#define WS_SHIFT  1536     // 512
#define WS_ESLOT  2048     // 512 entropy slots, atomic (zeroed)
#define WS_GF     2560     // 16384, G final (128x128)
#define WS_WHI    19456    // 65536 ushorts (32768 floats)
#define WS_WLO    52224    // 65536 ushorts
#define N_ESLOT   512
#define WS_ZERO_FLOATS 2560

#define GRAM_BLOCKS 512    // G partials: GRAM_BLOCKS x 16384 floats in d_out scratch

__device__ __forceinline__ unsigned short f2bf(float f) {
    unsigned u = __float_as_uint(f);
    unsigned r = (u + 0x7FFFu + ((u >> 16) & 1u)) >> 16;   // RNE
    return (unsigned short)r;
}
__device__ __forceinline__ float bf2f(unsigned short h) {
    return __uint_as_float(((unsigned)h) << 16);
}

// K1a: Gram partials G_b = A_b^T A_b (3-term split-bf16 MFMA) + colsum(A).
__global__ __launch_bounds__(256) void k1a_gram(const float* __restrict__ A,
                                                float* __restrict__ Gpart,
                                                float* __restrict__ ws, int Brows)
{
    __shared__ float As[32][133];
    __shared__ float s_lds[128];
    const int t = threadIdx.x;
    const int wave = t >> 6, lane = t & 63, lg = lane >> 4, lm = lane & 15;
    const int rowsPerBlk = Brows / GRAM_BLOCKS;   // 256
    const int r0 = blockIdx.x * rowsPerBlk;

    if (t < 128) s_lds[t] = 0.f;
    float s_part[4] = {0.f, 0.f, 0.f, 0.f};

    f32x4 acc[16];
#pragma unroll
    for (int i = 0; i < 16; ++i) acc[i] = (f32x4){0.f, 0.f, 0.f, 0.f};

    for (int kk = 0; kk < rowsPerBlk; kk += 32) {
        __syncthreads();
#pragma unroll
        for (int i = 0; i < 4; ++i) {
            int fi = t + i * 256;
            int row = fi >> 5, c4 = (fi & 31) * 4;
            float4 v = *(const float4*)(A + (size_t)(r0 + kk + row) * DIN + c4);
            *(float4*)&As[row][c4] = v;
            s_part[0] += v.x; s_part[1] += v.y; s_part[2] += v.z; s_part[3] += v.w;
        }
        __syncthreads();

        short8 fh[8], fl[8];
#pragma unroll
        for (int f = 0; f < 8; ++f) {
#pragma unroll
            for (int j = 0; j < 8; ++j) {
                float v = As[lg * 8 + j][f * 16 + lm];
                unsigned uv = __float_as_uint(v);
                float lo = v - __uint_as_float(uv & 0xFFFF0000u);
                fh[f][j] = (short)(uv >> 16);
                fl[f][j] = (short)(__float_as_uint(lo) >> 16);
            }
        }
        short8 ah0, al0, ah1, al1;
#pragma unroll
        for (int j = 0; j < 8; ++j) {
            float v0 = As[lg * 8 + j][wave * 32 + lm];
            float v1 = As[lg * 8 + j][wave * 32 + 16 + lm];
            unsigned u0 = __float_as_uint(v0), u1 = __float_as_uint(v1);
            float l0 = v0 - __uint_as_float(u0 & 0xFFFF0000u);
            float l1 = v1 - __uint_as_float(u1 & 0xFFFF0000u);
            ah0[j] = (short)(u0 >> 16);
            al0[j] = (short)(__float_as_uint(l0) >> 16);
            ah1[j] = (short)(u1 >> 16);
            al1[j] = (short)(__float_as_uint(l1) >> 16);
        }

#pragma unroll
        for (int tj = 0; tj < 8; ++tj) {
            acc[tj]     = __builtin_amdgcn_mfma_f32_16x16x32_bf16(al0, fh[tj], acc[tj], 0, 0, 0);
            acc[tj]     = __builtin_amdgcn_mfma_f32_16x16x32_bf16(ah0, fl[tj], acc[tj], 0, 0, 0);
            acc[tj]     = __builtin_amdgcn_mfma_f32_16x16x32_bf16(ah0, fh[tj], acc[tj], 0, 0, 0);
            acc[8 + tj] = __builtin_amdgcn_mfma_f32_16x16x32_bf16(al1, fh[tj], acc[8 + tj], 0, 0, 0);
            acc[8 + tj] = __builtin_amdgcn_mfma_f32_16x16x32_bf16(ah1, fl[tj], acc[8 + tj], 0, 0, 0);
            acc[8 + tj] = __builtin_amdgcn_mfma_f32_16x16x32_bf16(ah1, fh[tj], acc[8 + tj], 0, 0, 0);
        }
    }

#pragma unroll
    for (int j = 0; j < 4; ++j) atomicAdd(&s_lds[(t & 31) * 4 + j], s_part[j]);
    __syncthreads();
    if (t < 128) atomicAdd(ws + WS_COLSA + (blockIdx.x & 7) * 128 + t, s_lds[t]);

    float* Gs = Gpart + (size_t)blockIdx.x * 16384;
#pragma unroll
    for (int a2 = 0; a2 < 2; ++a2) {
#pragma unroll
        for (int tj = 0; tj < 8; ++tj) {
#pragma unroll
            for (int g = 0; g < 4; ++g) {
                int gi = (2 * wave + a2) * 16 + lg * 4 + g;
                int gj = tj * 16 + lm;
                Gs[gi * 128 + gj] = acc[a2 * 8 + tj][g];
            }
        }
    }
}

// K1b: reduce GRAM_BLOCKS partials -> G final in ws
__global__ __launch_bounds__(256) void k1b_sumG(const float* __restrict__ Gpart,
                                                float* __restrict__ ws)
{
    int i = blockIdx.x * 256 + threadIdx.x;   // 0..16383
    float v = 0.f;
#pragma unroll 8
    for (int s = 0; s < GRAM_BLOCKS; ++s) v += Gpart[(size_t)s * 16384 + i];
    ws[WS_GF + i] = v;
}

// K2: per-column BN stats from Gram + fused W'-pack (W' = W*scale).
__global__ __launch_bounds__(128) void k2_finalize(
    const float* __restrict__ W, const float* __restrict__ gamma,
    const float* __restrict__ beta, float* __restrict__ ws,
    unsigned short* __restrict__ Whi, unsigned short* __restrict__ Wlo, int Brows)
{
    __shared__ float wcol[128];
    __shared__ float red[4];
    __shared__ float sres;
    const int t = threadIdx.x, n = blockIdx.x;
    wcol[t] = W[(size_t)t * UNITS + n];
    __syncthreads();
    const float* GF = ws + WS_GF;
    float q = 0.f;
#pragma unroll 8
    for (int i = 0; i < 128; ++i) q += GF[i * 128 + t] * wcol[i];
    q *= wcol[t];
    float csa = 0.f;
#pragma unroll
    for (int sl = 0; sl < 8; ++sl) csa += ws[WS_COLSA + sl * 128 + t];
    float mp = csa * wcol[t];
#pragma unroll
    for (int off = 32; off; off >>= 1) {
        q  += __shfl_xor(q, off, 64);
        mp += __shfl_xor(mp, off, 64);
    }
    if ((t & 63) == 0) { red[(t >> 6) * 2] = q; red[(t >> 6) * 2 + 1] = mp; }
    __syncthreads();
    if (t == 0) {
        float sumsq = red[0] + red[2], ssum = red[1] + red[3];
        float invB = 1.0f / (float)Brows;
        float mean = ssum * invB;
        float var  = sumsq * invB - mean * mean;
        float rstd = rsqrtf(var + 1e-3f);
        float sc   = rstd * gamma[n];
        ws[WS_SCALE + n] = sc;
        ws[WS_SHIFT + n] = beta[n] - mean * sc;
        sres = sc;
    }
    __syncthreads();
    float v = wcol[t] * sres;
    int c = t >> 5, j = t & 7, lane = ((t >> 3) & 3) * 16 + (n & 15), t8 = n >> 4;
    int dst = (((c * 32 + t8) * 64 + lane) << 3) + j;
    unsigned short hi = f2bf(v);
    Whi[dst] = hi;
    Wlo[dst] = f2bf(v - bf2f(hi));
}

// K3: swapped-operand fused kernel (r11/r12 verified structure). 256 thr =
// 4 waves x 16 rows x 512 cols; W LDS-staged (global_load_lds, dbuf, 8 stages);
// 2 blocks/CU phase overlap. Sparsemax tail: REGISTER candidate compaction
// (c0..c3, compile-time-indexed insert; ballot fallback to full-scan) — no LDS,
// no barriers, no spill. Entropy over support only (exact).
__global__ __launch_bounds__(256, 2) void k3_fused(
    const float* __restrict__ A, const unsigned short* __restrict__ Whi,
    const unsigned short* __restrict__ Wlo, const float* __restrict__ prior,
    float* __restrict__ out, float* __restrict__ ws)
{
    __shared__ short8 wb[2][2][16][64];   // [dbuf][hi/lo][tile][lane] = 64 KB

    const int tid = threadIdx.x;
    const int wave = tid >> 6, lane = tid & 63, lg = lane >> 4, lm = lane & 15;
    const int r0 = blockIdx.x * 64 + wave * 16;

    // A fragments (B-operand of the swapped mfma): row = r0+lm, k = lg*8+j
    short8 ahi[4], alo[4];
    const float* arow = A + (size_t)(r0 + lm) * DIN + lg * 8;
#pragma unroll
    for (int c = 0; c < 4; ++c) {
        float4 f0 = *(const float4*)(arow + c * 32);
        float4 f1 = *(const float4*)(arow + c * 32 + 4);
        float fv[8] = {f0.x, f0.y, f0.z, f0.w, f1.x, f1.y, f1.z, f1.w};
#pragma unroll
        for (int j = 0; j < 8; ++j) {
            unsigned uv = __float_as_uint(fv[j]);
            float lo = fv[j] - __uint_as_float(uv & 0xFFFF0000u);
            ahi[c][j] = (short)(uv >> 16);
            alo[c][j] = (short)(__float_as_uint(lo) >> 16);
        }
    }

#define K3_STAGE(s, buf)                                                          \
    {                                                                             \
        const int H_ = (s) >> 2, c_ = (s) & 3;                                    \
        const unsigned short* srcH_ = Whi + (size_t)((c_ * 32 + H_ * 16) * 64) * 8;\
        const unsigned short* srcL_ = Wlo + (size_t)((c_ * 32 + H_ * 16) * 64) * 8;\
        _Pragma("unroll")                                                         \
        for (int i_ = 0; i_ < 8; ++i_) {                                          \
            int q_ = i_ * 256 + tid;                                              \
            const unsigned short* src_ = (q_ >> 10) ? srcL_ + (size_t)(q_ & 1023) * 8 \
                                                    : srcH_ + (size_t)(q_ & 1023) * 8; \
            __builtin_amdgcn_global_load_lds(                                     \
                (const __attribute__((address_space(1))) void*)src_,              \
                (__attribute__((address_space(3))) void*)&wb[buf][q_ >> 10][(q_ >> 6) & 15][q_ & 63], \
                16, 0, 0);                                                        \
        }                                                                         \
    }

    // acc[t][g] = X_bn[r=lm][n = t*16 + lg*4 + g]; init = shift[n]
    f32x4 acc[32];
#pragma unroll
    for (int t = 0; t < 32; ++t)
        acc[t] = *(const f32x4*)(ws + WS_SHIFT + t * 16 + lg * 4);

    K3_STAGE(0, 0);
    asm volatile("s_waitcnt vmcnt(0)" ::: "memory");
    __syncthreads();

    float m = -3.4e38f;   // row max, folded per col-half
#pragma unroll
    for (int H = 0; H < 2; ++H) {
#pragma unroll
        for (int c = 0; c < 4; ++c) {
            const int s = H * 4 + c;
            if (s == 0) { K3_STAGE(1, 1); }
            else if (s == 1) { K3_STAGE(2, 0); }
            else if (s == 2) { K3_STAGE(3, 1); }
            else if (s == 3) { K3_STAGE(4, 0); }
            else if (s == 4) { K3_STAGE(5, 1); }
            else if (s == 5) { K3_STAGE(6, 0); }
            else if (s == 6) { K3_STAGE(7, 1); }
            const int buf = s & 1;
#pragma unroll
            for (int t = 0; t < 16; ++t) {
                short8 h = wb[buf][0][t][lane];
                short8 l = wb[buf][1][t][lane];
                acc[H * 16 + t] = __builtin_amdgcn_mfma_f32_16x16x32_bf16(h, alo[c], acc[H * 16 + t], 0, 0, 0);
                acc[H * 16 + t] = __builtin_amdgcn_mfma_f32_16x16x32_bf16(l, ahi[c], acc[H * 16 + t], 0, 0, 0);
                acc[H * 16 + t] = __builtin_amdgcn_mfma_f32_16x16x32_bf16(h, ahi[c], acc[H * 16 + t], 0, 0, 0);
            }
            if (s < 7) {
                asm volatile("s_waitcnt vmcnt(0)" ::: "memory");
                __syncthreads();
            }
        }
        // prior-mul + max for this col-half (overlaps next half's prefetch)
        const float* prow = prior + (size_t)(r0 + lm) * UNITS + lg * 4;
#pragma unroll
        for (int t = 0; t < 16; ++t) {
            float4 p = *(const float4*)(prow + (H * 16 + t) * 16);
            acc[H * 16 + t][0] *= p.x;
            acc[H * 16 + t][1] *= p.y;
            acc[H * 16 + t][2] *= p.z;
            acc[H * 16 + t][3] *= p.w;
            m = fmaxf(m, fmaxf(fmaxf(acc[H * 16 + t][0], acc[H * 16 + t][1]),
                               fmaxf(acc[H * 16 + t][2], acc[H * 16 + t][3])));
        }
    }

    // combine the row's 4 lanes (xor 16, 32)
    m = fmaxf(m, __shfl_xor(m, 16, 64));
    m = fmaxf(m, __shfl_xor(m, 32, 64));

    // ---- pass 1 (fused): S,K at tau0 = m-1 + REGISTER candidate compaction ----
    const float tau0 = m - 1.0f;
    float S = 0.f, K = 0.f;
    float c0 = 0.f, c1 = 0.f, c2 = 0.f, c3 = 0.f;
    int myc = 0;
#pragma unroll
    for (int t = 0; t < 32; ++t) {
#pragma unroll
        for (int g = 0; g < 4; ++g) {
            float v = acc[t][g];
            if (v > tau0) {
                S += v; K += 1.f;
                if (myc == 0) c0 = v;
                else if (myc == 1) c1 = v;
                else if (myc == 2) c2 = v;
                else if (myc == 3) c3 = v;
                ++myc;
            }
        }
    }
    unsigned long long ovf = __ballot(myc > 4);

    S += __shfl_xor(S, 16, 64); S += __shfl_xor(S, 32, 64);
    K += __shfl_xor(K, 16, 64); K += __shfl_xor(K, 32, 64);
    float tau = tau0;
    {
        float nt = (S - 1.0f) / K;
        if (nt > tau) tau = nt;
    }

    float ent = 0.f;
    if (ovf == 0ull) {
        // ---- iters 2+: scan this lane's <=4 register candidates ----
        for (int it = 0; it < 23; ++it) {
            float S2 = 0.f, K2 = 0.f;
            if (myc > 0 && c0 > tau) { S2 += c0; K2 += 1.f; }
            if (myc > 1 && c1 > tau) { S2 += c1; K2 += 1.f; }
            if (myc > 2 && c2 > tau) { S2 += c2; K2 += 1.f; }
            if (myc > 3 && c3 > tau) { S2 += c3; K2 += 1.f; }
            S2 += __shfl_xor(S2, 16, 64); S2 += __shfl_xor(S2, 32, 64);
            K2 += __shfl_xor(K2, 16, 64); K2 += __shfl_xor(K2, 32, 64);
            float nt = (S2 - 1.0f) / K2;
            int chg = (nt > tau);
            if (chg) tau = nt;
            if (__ballot(chg) == 0ull) break;
        }
        // entropy from candidates only (non-candidates have v=0 -> exact 0 term)
        if (myc > 0) { float v = c0 - tau; if (v > 0.f) ent -= v * __logf(v + 1e-15f); }
        if (myc > 1) { float v = c1 - tau; if (v > 0.f) ent -= v * __logf(v + 1e-15f); }
        if (myc > 2) { float v = c2 - tau; if (v > 0.f) ent -= v * __logf(v + 1e-15f); }
        if (myc > 3) { float v = c3 - tau; if (v > 0.f) ent -= v * __logf(v + 1e-15f); }
    } else {
        // fallback: verified full-scan ballot Newton + full entropy
        for (int it = 0; it < 23; ++it) {
            float S2 = 0.f, K2 = 0.f;
#pragma unroll
            for (int t = 0; t < 32; ++t) {
#pragma unroll
                for (int g = 0; g < 4; ++g) {
                    float v = acc[t][g];
                    if (v > tau) { S2 += v; K2 += 1.f; }
                }
            }
            S2 += __shfl_xor(S2, 16, 64); S2 += __shfl_xor(S2, 32, 64);
            K2 += __shfl_xor(K2, 16, 64); K2 += __shfl_xor(K2, 32, 64);
            float nt = (S2 - 1.0f) / K2;
            int chg = (nt > tau);
            if (chg) tau = nt;
            if (__ballot(chg) == 0ull) break;
        }
#pragma unroll
        for (int t = 0; t < 32; ++t) {
#pragma unroll
            for (int g = 0; g < 4; ++g) {
                float v = fmaxf(acc[t][g] - tau, 0.f);
                if (v > 0.f) ent -= v * __logf(v + 1e-15f);
            }
        }
    }

    // ---- mask write (no logs) ----
    float* orow = out + (size_t)(r0 + lm) * UNITS + lg * 4;
#pragma unroll
    for (int t = 0; t < 32; ++t) {
        float4 o;
        o.x = fmaxf(acc[t][0] - tau, 0.f);
        o.y = fmaxf(acc[t][1] - tau, 0.f);
        o.z = fmaxf(acc[t][2] - tau, 0.f);
        o.w = fmaxf(acc[t][3] - tau, 0.f);
        *(float4*)(orow + t * 16) = o;
    }

#pragma unroll
    for (int off = 32; off; off >>= 1) ent += __shfl_xor(ent, off, 64);
    if (lane == 0)
        atomicAdd(&ws[WS_ESLOT + ((blockIdx.x * 4 + wave) & (N_ESLOT - 1))], ent);
#undef K3_STAGE
}

// K4: reduce entropy slots -> scalar loss
__global__ void k4_loss(const float* __restrict__ ws, float* __restrict__ out_loss,
                        int Brows)
{
    __shared__ float sh[512];
    int t = threadIdx.x;
    sh[t] = ws[WS_ESLOT + t];
    __syncthreads();
    for (int s = 256; s > 0; s >>= 1) {
        if (t < s) sh[t] += sh[t + s];
        __syncthreads();
    }
    if (t == 0) out_loss[0] = 1e-3f * (sh[0] / (float)Brows) * (1.0f / 3.0f);
}

extern "C" void kernel_launch(void* const* d_in, const int* in_sizes, int n_in,
                              void* d_out, int out_size, void* d_ws, size_t ws_size,
                              hipStream_t stream)
{
    const float* inputs = (const float*)d_in[0];
    const float* prior  = (const float*)d_in[1];
    const float* Wm     = (const float*)d_in[2];
    const float* gamma  = (const float*)d_in[3];
    const float* beta   = (const float*)d_in[4];
    float* out = (float*)d_out;
    float* ws  = (float*)d_ws;
    unsigned short* Whi = (unsigned short*)(ws + WS_WHI);
    unsigned short* Wlo = (unsigned short*)(ws + WS_WLO);
    const int Brows = in_sizes[1] / UNITS;   // 131072

    // d_out doubles as Gram-partial scratch (33.5 MB) before k3 overwrites it.
    float* Gpart = out;

    hipMemsetAsync(ws, 0, WS_ZERO_FLOATS * sizeof(float), stream);

    k1a_gram<<<GRAM_BLOCKS, 256, 0, stream>>>(inputs, Gpart, ws, Brows);
    k1b_sumG<<<64, 256, 0, stream>>>(Gpart, ws);
    k2_finalize<<<UNITS, 128, 0, stream>>>(Wm, gamma, beta, ws, Whi, Wlo, Brows);
    k3_fused<<<Brows / 64, 256, 0, stream>>>(inputs, Whi, Wlo, prior, out, ws);
    k4_loss<<<1, N_ESLOT, 0, stream>>>(ws, out + (size_t)Brows * UNITS, Brows);
}

// Round 16
// 260.917 us; speedup vs baseline: 1.5691x; 1.3068x over previous
//
#include <hip/hip_runtime.h>
#include <math.h>

typedef __attribute__((ext_vector_type(8))) short short8;
typedef __attribute__((ext_vector_type(4))) float f32x4;

#define UNITS 512
#define DIN 128

// ws float offsets:
#define WS_COLSA  0        // 8 slots x 128, colsum(A), atomic (zeroed)
#define WS_SCALE  1024     // 512
#define WS_SHIFT  1536     // 512
#define WS_ESLOT  2048     // 512 entropy slots, atomic (zeroed)
#define WS_GF     2560     // 16384, G final (128x128)
#define WS_WHI    19456    // 65536 ushorts (32768 floats)
#define WS_WLO    52224    // 65536 ushorts
#define N_ESLOT   512
#define WS_ZERO_FLOATS 2560

#define GRAM_BLOCKS 512    // G partials: GRAM_BLOCKS x 16384 floats in d_out scratch
#define NCAP 64            // per-lane candidate slots (64 KB / 4B / 256 threads)

__device__ __forceinline__ unsigned short f2bf(float f) {
    unsigned u = __float_as_uint(f);
    unsigned r = (u + 0x7FFFu + ((u >> 16) & 1u)) >> 16;   // RNE
    return (unsigned short)r;
}
__device__ __forceinline__ float bf2f(unsigned short h) {
    return __uint_as_float(((unsigned)h) << 16);
}

// K1a: Gram partials G_b = A_b^T A_b (3-term split-bf16 MFMA) + colsum(A).
__global__ __launch_bounds__(256) void k1a_gram(const float* __restrict__ A,
                                                float* __restrict__ Gpart,
                                                float* __restrict__ ws, int Brows)
{
    __shared__ float As[32][133];
    __shared__ float s_lds[128];
    const int t = threadIdx.x;
    const int wave = t >> 6, lane = t & 63, lg = lane >> 4, lm = lane & 15;
    const int rowsPerBlk = Brows / GRAM_BLOCKS;   // 256
    const int r0 = blockIdx.x * rowsPerBlk;

    if (t < 128) s_lds[t] = 0.f;
    float s_part[4] = {0.f, 0.f, 0.f, 0.f};

    f32x4 acc[16];
#pragma unroll
    for (int i = 0; i < 16; ++i) acc[i] = (f32x4){0.f, 0.f, 0.f, 0.f};

    for (int kk = 0; kk < rowsPerBlk; kk += 32) {
        __syncthreads();
#pragma unroll
        for (int i = 0; i < 4; ++i) {
            int fi = t + i * 256;
            int row = fi >> 5, c4 = (fi & 31) * 4;
            float4 v = *(const float4*)(A + (size_t)(r0 + kk + row) * DIN + c4);
            *(float4*)&As[row][c4] = v;
            s_part[0] += v.x; s_part[1] += v.y; s_part[2] += v.z; s_part[3] += v.w;
        }
        __syncthreads();

        short8 fh[8], fl[8];
#pragma unroll
        for (int f = 0; f < 8; ++f) {
#pragma unroll
            for (int j = 0; j < 8; ++j) {
                float v = As[lg * 8 + j][f * 16 + lm];
                unsigned uv = __float_as_uint(v);
                float lo = v - __uint_as_float(uv & 0xFFFF0000u);
                fh[f][j] = (short)(uv >> 16);
                fl[f][j] = (short)(__float_as_uint(lo) >> 16);
            }
        }
        short8 ah0, al0, ah1, al1;
#pragma unroll
        for (int j = 0; j < 8; ++j) {
            float v0 = As[lg * 8 + j][wave * 32 + lm];
            float v1 = As[lg * 8 + j][wave * 32 + 16 + lm];
            unsigned u0 = __float_as_uint(v0), u1 = __float_as_uint(v1);
            float l0 = v0 - __uint_as_float(u0 & 0xFFFF0000u);
            float l1 = v1 - __uint_as_float(u1 & 0xFFFF0000u);
            ah0[j] = (short)(u0 >> 16);
            al0[j] = (short)(__float_as_uint(l0) >> 16);
            ah1[j] = (short)(u1 >> 16);
            al1[j] = (short)(__float_as_uint(l1) >> 16);
        }

#pragma unroll
        for (int tj = 0; tj < 8; ++tj) {
            acc[tj]     = __builtin_amdgcn_mfma_f32_16x16x32_bf16(al0, fh[tj], acc[tj], 0, 0, 0);
            acc[tj]     = __builtin_amdgcn_mfma_f32_16x16x32_bf16(ah0, fl[tj], acc[tj], 0, 0, 0);
            acc[tj]     = __builtin_amdgcn_mfma_f32_16x16x32_bf16(ah0, fh[tj], acc[tj], 0, 0, 0);
            acc[8 + tj] = __builtin_amdgcn_mfma_f32_16x16x32_bf16(al1, fh[tj], acc[8 + tj], 0, 0, 0);
            acc[8 + tj] = __builtin_amdgcn_mfma_f32_16x16x32_bf16(ah1, fl[tj], acc[8 + tj], 0, 0, 0);
            acc[8 + tj] = __builtin_amdgcn_mfma_f32_16x16x32_bf16(ah1, fh[tj], acc[8 + tj], 0, 0, 0);
        }
    }

#pragma unroll
    for (int j = 0; j < 4; ++j) atomicAdd(&s_lds[(t & 31) * 4 + j], s_part[j]);
    __syncthreads();
    if (t < 128) atomicAdd(ws + WS_COLSA + (blockIdx.x & 7) * 128 + t, s_lds[t]);

    float* Gs = Gpart + (size_t)blockIdx.x * 16384;
#pragma unroll
    for (int a2 = 0; a2 < 2; ++a2) {
#pragma unroll
        for (int tj = 0; tj < 8; ++tj) {
#pragma unroll
            for (int g = 0; g < 4; ++g) {
                int gi = (2 * wave + a2) * 16 + lg * 4 + g;
                int gj = tj * 16 + lm;
                Gs[gi * 128 + gj] = acc[a2 * 8 + tj][g];
            }
        }
    }
}

// K1b: reduce GRAM_BLOCKS partials -> G final in ws
__global__ __launch_bounds__(256) void k1b_sumG(const float* __restrict__ Gpart,
                                                float* __restrict__ ws)
{
    int i = blockIdx.x * 256 + threadIdx.x;   // 0..16383
    float v = 0.f;
#pragma unroll 8
    for (int s = 0; s < GRAM_BLOCKS; ++s) v += Gpart[(size_t)s * 16384 + i];
    ws[WS_GF + i] = v;
}

// K2: per-column BN stats from Gram + fused W'-pack (W' = W*scale).
__global__ __launch_bounds__(128) void k2_finalize(
    const float* __restrict__ W, const float* __restrict__ gamma,
    const float* __restrict__ beta, float* __restrict__ ws,
    unsigned short* __restrict__ Whi, unsigned short* __restrict__ Wlo, int Brows)
{
    __shared__ float wcol[128];
    __shared__ float red[4];
    __shared__ float sres;
    const int t = threadIdx.x, n = blockIdx.x;
    wcol[t] = W[(size_t)t * UNITS + n];
    __syncthreads();
    const float* GF = ws + WS_GF;
    float q = 0.f;
#pragma unroll 8
    for (int i = 0; i < 128; ++i) q += GF[i * 128 + t] * wcol[i];
    q *= wcol[t];
    float csa = 0.f;
#pragma unroll
    for (int sl = 0; sl < 8; ++sl) csa += ws[WS_COLSA + sl * 128 + t];
    float mp = csa * wcol[t];
#pragma unroll
    for (int off = 32; off; off >>= 1) {
        q  += __shfl_xor(q, off, 64);
        mp += __shfl_xor(mp, off, 64);
    }
    if ((t & 63) == 0) { red[(t >> 6) * 2] = q; red[(t >> 6) * 2 + 1] = mp; }
    __syncthreads();
    if (t == 0) {
        float sumsq = red[0] + red[2], ssum = red[1] + red[3];
        float invB = 1.0f / (float)Brows;
        float mean = ssum * invB;
        float var  = sumsq * invB - mean * mean;
        float rstd = rsqrtf(var + 1e-3f);
        float sc   = rstd * gamma[n];
        ws[WS_SCALE + n] = sc;
        ws[WS_SHIFT + n] = beta[n] - mean * sc;
        sres = sc;
    }
    __syncthreads();
    float v = wcol[t] * sres;
    int c = t >> 5, j = t & 7, lane = ((t >> 3) & 3) * 16 + (n & 15), t8 = n >> 4;
    int dst = (((c * 32 + t8) * 64 + lane) << 3) + j;
    unsigned short hi = f2bf(v);
    Whi[dst] = hi;
    Wlo[dst] = f2bf(v - bf2f(hi));
}

// K3: swapped-operand fused kernel (r12-verified best). 256 thr = 4 waves x
// 16 rows x 512 cols; W LDS-staged (global_load_lds, dbuf, 8 stages);
// 2 blocks/CU phase overlap. Sparsemax tail via PER-LANE LDS candidate
// compaction (conflict-free layout, no atomics): first Newton pass fused with
// compaction, iters 2+ scan ~2 candidates/lane, entropy from candidates (exact).
__global__ __launch_bounds__(256, 2) void k3_fused(
    const float* __restrict__ A, const unsigned short* __restrict__ Whi,
    const unsigned short* __restrict__ Wlo, const float* __restrict__ prior,
    float* __restrict__ out, float* __restrict__ ws)
{
    __shared__ short8 wb[2][2][16][64];   // 64 KB; aliased as cand[] after GEMM
    float* cand = (float*)wb;             // cand[slot*256 + tid], bank = tid%32

    const int tid = threadIdx.x;
    const int wave = tid >> 6, lane = tid & 63, lg = lane >> 4, lm = lane & 15;
    const int r0 = blockIdx.x * 64 + wave * 16;

    // A fragments (B-operand of the swapped mfma): row = r0+lm, k = lg*8+j
    short8 ahi[4], alo[4];
    const float* arow = A + (size_t)(r0 + lm) * DIN + lg * 8;
#pragma unroll
    for (int c = 0; c < 4; ++c) {
        float4 f0 = *(const float4*)(arow + c * 32);
        float4 f1 = *(const float4*)(arow + c * 32 + 4);
        float fv[8] = {f0.x, f0.y, f0.z, f0.w, f1.x, f1.y, f1.z, f1.w};
#pragma unroll
        for (int j = 0; j < 8; ++j) {
            unsigned uv = __float_as_uint(fv[j]);
            float lo = fv[j] - __uint_as_float(uv & 0xFFFF0000u);
            ahi[c][j] = (short)(uv >> 16);
            alo[c][j] = (short)(__float_as_uint(lo) >> 16);
        }
    }

#define K3_STAGE(s, buf)                                                          \
    {                                                                             \
        const int H_ = (s) >> 2, c_ = (s) & 3;                                    \
        const unsigned short* srcH_ = Whi + (size_t)((c_ * 32 + H_ * 16) * 64) * 8;\
        const unsigned short* srcL_ = Wlo + (size_t)((c_ * 32 + H_ * 16) * 64) * 8;\
        _Pragma("unroll")                                                         \
        for (int i_ = 0; i_ < 8; ++i_) {                                          \
            int q_ = i_ * 256 + tid;                                              \
            const unsigned short* src_ = (q_ >> 10) ? srcL_ + (size_t)(q_ & 1023) * 8 \
                                                    : srcH_ + (size_t)(q_ & 1023) * 8; \
            __builtin_amdgcn_global_load_lds(                                     \
                (const __attribute__((address_space(1))) void*)src_,              \
                (__attribute__((address_space(3))) void*)&wb[buf][q_ >> 10][(q_ >> 6) & 15][q_ & 63], \
                16, 0, 0);                                                        \
        }                                                                         \
    }

    // acc[t][g] = X_bn[r=lm][n = t*16 + lg*4 + g]; init = shift[n]
    f32x4 acc[32];
#pragma unroll
    for (int t = 0; t < 32; ++t)
        acc[t] = *(const f32x4*)(ws + WS_SHIFT + t * 16 + lg * 4);

    K3_STAGE(0, 0);
    asm volatile("s_waitcnt vmcnt(0)" ::: "memory");
    __syncthreads();

    float m = -3.4e38f;   // row max, folded per col-half
#pragma unroll
    for (int H = 0; H < 2; ++H) {
#pragma unroll
        for (int c = 0; c < 4; ++c) {
            const int s = H * 4 + c;
            if (s == 0) { K3_STAGE(1, 1); }
            else if (s == 1) { K3_STAGE(2, 0); }
            else if (s == 2) { K3_STAGE(3, 1); }
            else if (s == 3) { K3_STAGE(4, 0); }
            else if (s == 4) { K3_STAGE(5, 1); }
            else if (s == 5) { K3_STAGE(6, 0); }
            else if (s == 6) { K3_STAGE(7, 1); }
            const int buf = s & 1;
#pragma unroll
            for (int t = 0; t < 16; ++t) {
                short8 h = wb[buf][0][t][lane];
                short8 l = wb[buf][1][t][lane];
                acc[H * 16 + t] = __builtin_amdgcn_mfma_f32_16x16x32_bf16(h, alo[c], acc[H * 16 + t], 0, 0, 0);
                acc[H * 16 + t] = __builtin_amdgcn_mfma_f32_16x16x32_bf16(l, ahi[c], acc[H * 16 + t], 0, 0, 0);
                acc[H * 16 + t] = __builtin_amdgcn_mfma_f32_16x16x32_bf16(h, ahi[c], acc[H * 16 + t], 0, 0, 0);
            }
            if (s < 7) {
                asm volatile("s_waitcnt vmcnt(0)" ::: "memory");
                __syncthreads();
            }
        }
        // prior-mul + max for this col-half (overlaps next half's prefetch)
        const float* prow = prior + (size_t)(r0 + lm) * UNITS + lg * 4;
#pragma unroll
        for (int t = 0; t < 16; ++t) {
            float4 p = *(const float4*)(prow + (H * 16 + t) * 16);
            acc[H * 16 + t][0] *= p.x;
            acc[H * 16 + t][1] *= p.y;
            acc[H * 16 + t][2] *= p.z;
            acc[H * 16 + t][3] *= p.w;
            m = fmaxf(m, fmaxf(fmaxf(acc[H * 16 + t][0], acc[H * 16 + t][1]),
                               fmaxf(acc[H * 16 + t][2], acc[H * 16 + t][3])));
        }
    }

    // combine the row's 4 lanes (xor 16, 32)
    m = fmaxf(m, __shfl_xor(m, 16, 64));
    m = fmaxf(m, __shfl_xor(m, 32, 64));

    // ---- pass 1 (fused): S,K at tau0 = m-1 + per-lane candidate compaction ----
    __syncthreads();   // all waves done with wb before cand aliases it
    const float tau0 = m - 1.0f;
    float S = 0.f, K = 0.f;
    int myc = 0;
#pragma unroll
    for (int t = 0; t < 32; ++t) {
#pragma unroll
        for (int g = 0; g < 4; ++g) {
            float v = acc[t][g];
            if (v > tau0) {
                S += v; K += 1.f;
                if (myc < NCAP) cand[myc * 256 + tid] = v;
                ++myc;
            }
        }
    }
    unsigned long long ovf = __ballot(myc > NCAP);

    S += __shfl_xor(S, 16, 64); S += __shfl_xor(S, 32, 64);
    K += __shfl_xor(K, 16, 64); K += __shfl_xor(K, 32, 64);
    float tau = tau0;
    {
        float nt = (S - 1.0f) / K;
        if (nt > tau) tau = nt;
    }

    float ent = 0.f;
    if (ovf == 0ull) {
        // ---- iters 2+: scan only this lane's candidates (~2) ----
        for (int it = 0; it < 23; ++it) {
            float S2 = 0.f, K2 = 0.f;
            for (int i = 0; i < myc; ++i) {
                float v = cand[i * 256 + tid];
                if (v > tau) { S2 += v; K2 += 1.f; }
            }
            S2 += __shfl_xor(S2, 16, 64); S2 += __shfl_xor(S2, 32, 64);
            K2 += __shfl_xor(K2, 16, 64); K2 += __shfl_xor(K2, 32, 64);
            float nt = (S2 - 1.0f) / K2;
            int chg = (nt > tau);
            if (chg) tau = nt;
            if (__ballot(chg) == 0ull) break;
        }
        // entropy from candidates only (non-candidates have v=0 -> exact 0 term)
        for (int i = 0; i < myc; ++i) {
            float v = cand[i * 256 + tid] - tau;
            if (v > 0.f) ent -= v * __logf(v + 1e-15f);
        }
    } else {
        // fallback: verified full-scan ballot Newton + full entropy
        for (int it = 0; it < 23; ++it) {
            float S2 = 0.f, K2 = 0.f;
#pragma unroll
            for (int t = 0; t < 32; ++t) {
#pragma unroll
                for (int g = 0; g < 4; ++g) {
                    float v = acc[t][g];
                    if (v > tau) { S2 += v; K2 += 1.f; }
                }
            }
            S2 += __shfl_xor(S2, 16, 64); S2 += __shfl_xor(S2, 32, 64);
            K2 += __shfl_xor(K2, 16, 64); K2 += __shfl_xor(K2, 32, 64);
            float nt = (S2 - 1.0f) / K2;
            int chg = (nt > tau);
            if (chg) tau = nt;
            if (__ballot(chg) == 0ull) break;
        }
#pragma unroll
        for (int t = 0; t < 32; ++t) {
#pragma unroll
            for (int g = 0; g < 4; ++g) {
                float v = fmaxf(acc[t][g] - tau, 0.f);
                if (v > 0.f) ent -= v * __logf(v + 1e-15f);
            }
        }
    }

    // ---- mask write (no logs) ----
    float* orow = out + (size_t)(r0 + lm) * UNITS + lg * 4;
#pragma unroll
    for (int t = 0; t < 32; ++t) {
        float4 o;
        o.x = fmaxf(acc[t][0] - tau, 0.f);
        o.y = fmaxf(acc[t][1] - tau, 0.f);
        o.z = fmaxf(acc[t][2] - tau, 0.f);
        o.w = fmaxf(acc[t][3] - tau, 0.f);
        *(float4*)(orow + t * 16) = o;
    }

#pragma unroll
    for (int off = 32; off; off >>= 1) ent += __shfl_xor(ent, off, 64);
    if (lane == 0)
        atomicAdd(&ws[WS_ESLOT + ((blockIdx.x * 4 + wave) & (N_ESLOT - 1))], ent);
#undef K3_STAGE
}

// K4: reduce entropy slots -> scalar loss
__global__ void k4_loss(const float* __restrict__ ws, float* __restrict__ out_loss,
                        int Brows)
{
    __shared__ float sh[512];
    int t = threadIdx.x;
    sh[t] = ws[WS_ESLOT + t];
    __syncthreads();
    for (int s = 256; s > 0; s >>= 1) {
        if (t < s) sh[t] += sh[t + s];
        __syncthreads();
    }
    if (t == 0) out_loss[0] = 1e-3f * (sh[0] / (float)Brows) * (1.0f / 3.0f);
}

extern "C" void kernel_launch(void* const* d_in, const int* in_sizes, int n_in,
                              void* d_out, int out_size, void* d_ws, size_t ws_size,
                              hipStream_t stream)
{
    const float* inputs = (const float*)d_in[0];
    const float* prior  = (const float*)d_in[1];
    const float* Wm     = (const float*)d_in[2];
    const float* gamma  = (const float*)d_in[3];
    const float* beta   = (const float*)d_in[4];
    float* out = (float*)d_out;
    float* ws  = (float*)d_ws;
    unsigned short* Whi = (unsigned short*)(ws + WS_WHI);
    unsigned short* Wlo = (unsigned short*)(ws + WS_WLO);
    const int Brows = in_sizes[1] / UNITS;   // 131072

    // d_out doubles as Gram-partial scratch (33.5 MB) before k3 overwrites it.
    float* Gpart = out;

    hipMemsetAsync(ws, 0, WS_ZERO_FLOATS * sizeof(float), stream);

    k1a_gram<<<GRAM_BLOCKS, 256, 0, stream>>>(inputs, Gpart, ws, Brows);
    k1b_sumG<<<64, 256, 0, stream>>>(Gpart, ws);
    k2_finalize<<<UNITS, 128, 0, stream>>>(Wm, gamma, beta, ws, Whi, Wlo, Brows);
    k3_fused<<<Brows / 64, 256, 0, stream>>>(inputs, Whi, Wlo, prior, out, ws);
    k4_loss<<<1, N_ESLOT, 0, stream>>>(ws, out + (size_t)Brows * UNITS, Brows);
}